// Round 21
// baseline (969.407 us; speedup 1.0000x reference)
//
#include <hip/hip_runtime.h>
#include <hip/hip_bf16.h>

#define NN 100000
#define NE 1600000
#define DIN 1000
#define BN_EPS 1e-3f
#define NB 391   // ceil(NN/256)

// output element offsets (concat of z, mu, logvar, de_feat, q, feat_x, gnn_z) — float32 out
#define OZ  ((size_t)0)
#define OMU ((size_t)NN*80)
#define OLV ((size_t)NN*96)
#define ODE ((size_t)NN*112)
#define OQ  ((size_t)NN*1112)
#define OFX ((size_t)NN*1127)
#define OGZ ((size_t)NN*1191)

typedef __attribute__((ext_vector_type(8))) short short8v;   // 8 bf16 (4 VGPRs)
typedef __attribute__((ext_vector_type(4))) short short4v;   // 4 bf16 (2 VGPRs)
typedef __attribute__((ext_vector_type(4))) float f32x4;     // MFMA accumulator

__device__ __forceinline__ float elu_f(float x) { return x > 0.f ? x : expf(x) - 1.f; }

// fp32 -> bf16 bits, round-to-nearest-even
__device__ __forceinline__ short f2bf(float f) {
    union { float f; unsigned u; } c; c.f = f;
    unsigned r = c.u + 0x7fffu + ((c.u >> 16) & 1u);
    return (short)(r >> 16);
}
// bf16 bits -> fp32
__device__ __forceinline__ float b2f(short s) {
    union { unsigned u; float f; } c; c.u = ((unsigned)(unsigned short)s) << 16; return c.f;
}
__device__ __forceinline__ float b2f_lo(unsigned p) {
    union { unsigned u; float f; } c; c.u = p << 16; return c.f;
}
__device__ __forceinline__ float b2f_hi(unsigned p) {
    union { unsigned u; float f; } c; c.u = p & 0xffff0000u; return c.f;
}

// Edge index may arrive as int32 or int64; logical element idx in flat (2*E) array.
__device__ __forceinline__ int edge_at(const void* ei, int is64, size_t idx) {
    if (is64) return (int)((const long long*)ei)[idx];
    return ((const int*)ei)[idx];
}

// ---------------- deg init + dtype detection (block 0) ----------------
__global__ __launch_bounds__(256) void k_deg_init(const int* __restrict__ ei,
                                                  float* __restrict__ deg, int* __restrict__ flag) {
    const int i = blockIdx.x * 256 + threadIdx.x;
    if (i < NN) deg[i] = 1.0f;
    if (blockIdx.x == 0) {
        __shared__ int nz;
        if (threadIdx.x == 0) nz = 0;
        __syncthreads();
        for (int j = threadIdx.x; j < 2048; j += 256)
            if (ei[2 * j + 1] != 0) nz = 1;
        __syncthreads();
        if (threadIdx.x == 0) flag[0] = (nz == 0) ? 1 : 0;  // 1 => int64
    }
}

__global__ __launch_bounds__(256) void k_deg_accum(const void* __restrict__ ei, const int* __restrict__ flag,
                                                   float* __restrict__ deg) {
    const int is64 = flag[0];
    int e = blockIdx.x * 256 + threadIdx.x;
    if (e < NE) atomicAdd(&deg[edge_at(ei, is64, (size_t)NE + e)], 1.0f);
}

// ---------------- CSR build: exclusive scan of in-edge counts ----------------
__global__ __launch_bounds__(256) void k_scan1(const float* __restrict__ deg, int* __restrict__ off,
                                               int* __restrict__ bsum, int* __restrict__ cursor) {
    __shared__ int s[256];
    const int t = threadIdx.x;
    const int i = blockIdx.x * 256 + t;
    const int vv = (i < NN) ? ((int)deg[i]) - 1 : 0;
    if (i < NN) cursor[i] = 0;
    s[t] = vv;
    __syncthreads();
    for (int d = 1; d < 256; d <<= 1) {
        const int u = (t >= d) ? s[t - d] : 0;
        __syncthreads();
        s[t] += u;
        __syncthreads();
    }
    if (i < NN) off[i] = s[t] - vv;           // exclusive, pre-block-offset
    if (t == 255) bsum[blockIdx.x] = s[t];    // block total
}

__global__ __launch_bounds__(512) void k_scan2(int* __restrict__ bsum) {
    __shared__ int s[512];
    const int t = threadIdx.x;
    const int vv = (t < NB) ? bsum[t] : 0;
    s[t] = vv;
    __syncthreads();
    for (int d = 1; d < 512; d <<= 1) {
        const int u = (t >= d) ? s[t - d] : 0;
        __syncthreads();
        s[t] += u;
        __syncthreads();
    }
    if (t < NB) bsum[t] = s[t] - vv;          // exclusive block prefix
}

__global__ __launch_bounds__(256) void k_scan3(int* __restrict__ off, const int* __restrict__ bsum) {
    const int i = blockIdx.x * 256 + threadIdx.x;
    if (i < NN) off[i] += bsum[blockIdx.x];
}

// interleaved CSR: one int2 {src, w_bits} per edge — single 8B scatter store
__global__ __launch_bounds__(256) void k_fill(const void* __restrict__ ei, const int* __restrict__ flag,
                                              const float* __restrict__ deg, const int* __restrict__ off,
                                              int* __restrict__ cursor, int2* __restrict__ csr_e) {
    const int is64 = flag[0];
    const int e = blockIdx.x * 256 + threadIdx.x;
    if (e >= NE) return;
    const int r = edge_at(ei, is64, e);
    const int c = edge_at(ei, is64, (size_t)NE + e);
    const float w = rsqrtf(deg[r]) * rsqrtf(deg[c]);
    const int p = atomicAdd(&cursor[c], 1);
    csr_e[off[c] + p] = make_int2(r, __float_as_int(w));
}

// ---------------- merged weight prep ----------------
// blocks 0..1023: enc0 w[1000][256] -> wt k-major granules (k zero-padded to 1024)
// blocks 1024..1279: dec1 w[64][1000] -> wt2[1024][64] (cols zero-padded)
__global__ __launch_bounds__(256) void k_wts(const float* __restrict__ w0, short* __restrict__ wt,
                                             const float* __restrict__ w1, short* __restrict__ wt2) {
    const int bid = blockIdx.x;
    if (bid < 1024) {
        const int tid = bid * 256 + threadIdx.x;   // 256*1024 elements
        const int c = tid >> 10;
        const int k = tid & 1023;
        wt[((size_t)(k >> 3) * 256 + c) * 8 + (k & 7)] = (k < DIN) ? f2bf(w0[(size_t)k * 256 + c]) : (short)0;
    } else {
        const int tid = (bid - 1024) * 256 + threadIdx.x;   // 1024*64 elements
        const int c = tid >> 6;
        const int k = tid & 63;
        wt2[(size_t)c * 64 + k] = (c < DIN) ? f2bf(w1[(size_t)k * DIN + c]) : (short)0;
    }
}

// ---------------- encoder L0 via MFMA: h1bf = bf16(ELU(BN(x @ w))) ----------------
// Block tile 128x256, 8 waves (2 row x 4 col), wave tile 64x64, K_STEP=32.
// Double-buffered single-barrier K-loop; epilogue stages the bf16 tile in LDS
// (reusing the staging pool) and writes h1bf in fully-coalesced 512B rows.
__global__ __launch_bounds__(512, 2) void k_enc0_mfma(
    const float* __restrict__ x, const short* __restrict__ wt, const float* __restrict__ bias,
    const float* __restrict__ g, const float* __restrict__ bb,
    const float* __restrict__ m, const float* __restrict__ v,
    short* __restrict__ h1bf)
{
    __shared__ short smem[24576];   // 48KB: As(2x4096) + Bs(2x8192); epilogue: 64x256 staging
    const int t = threadIdx.x;           // 0..511
    const int lane = t & 63;
    const int wave = t >> 6;             // 0..7
    const int wm = (wave >> 2) * 64;     // 0,64
    const int wn = (wave & 3) * 64;      // 0,64,128,192
    const int row0 = blockIdx.x * 128;

    f32x4 acc[4][4];
    #pragma unroll
    for (int mi = 0; mi < 4; ++mi)
        #pragma unroll
        for (int ni = 0; ni < 4; ++ni)
            acc[mi][ni] = (f32x4){0.f, 0.f, 0.f, 0.f};

    // A staging (coalesced): thread t = (row t>>3, float4-slot t&7), rows rA0, rA0+64
    const int kq = t & 7;
    const int rA0 = t >> 3;              // 0..63
    const int rA1 = rA0 + 64;            // 64..127
    const int gr0 = (row0 + rA0 < NN) ? (row0 + rA0) : (NN - 1);
    const int gr1 = (row0 + rA1 < NN) ? (row0 + rA1) : (NN - 1);
    const float* xb0 = x + (size_t)gr0 * DIN;
    const float* xb1 = x + (size_t)gr1 * DIN;
    const size_t aoff0 = (((kq >> 1) * 128) + rA0) * 8 + (kq & 1) * 4;
    const size_t aoff1 = (((kq >> 1) * 128) + rA1) * 8 + (kq & 1) * 4;

    // B staging: granules colB with kcB0 (0..1) and kcB1 (2..3)
    const int colB = t & 255;
    const int kcB0 = t >> 8;
    const int kcB1 = 2 + (t >> 8);
    const size_t boff0 = ((size_t)kcB0 * 256 + colB) * 8;
    const size_t boff1 = ((size_t)kcB1 * 256 + colB) * 8;

    const int kc = lane >> 4;    // 0..3
    const int lr = lane & 15;

    // ---- prologue: stage ks=0 into buf 0 ----
    {
        const float4 f0 = *reinterpret_cast<const float4*>(xb0 + kq * 4);
        const float4 f1 = *reinterpret_cast<const float4*>(xb1 + kq * 4);
        short4v p0, p1;
        p0[0] = f2bf(f0.x); p0[1] = f2bf(f0.y); p0[2] = f2bf(f0.z); p0[3] = f2bf(f0.w);
        p1[0] = f2bf(f1.x); p1[1] = f2bf(f1.y); p1[2] = f2bf(f1.z); p1[3] = f2bf(f1.w);
        *reinterpret_cast<short4v*>(&smem[aoff0]) = p0;
        *reinterpret_cast<short4v*>(&smem[aoff1]) = p1;
        *reinterpret_cast<short8v*>(&smem[8192 + boff0]) =
            *reinterpret_cast<const short8v*>(&wt[((size_t)kcB0 * 256 + colB) * 8]);
        *reinterpret_cast<short8v*>(&smem[8192 + boff1]) =
            *reinterpret_cast<const short8v*>(&wt[((size_t)kcB1 * 256 + colB) * 8]);
    }
    __syncthreads();

    for (int ks = 0; ks < 32; ++ks) {
        const int cur = ks & 1;
        const int nxt = cur ^ 1;
        const int abase_c = cur * 4096;
        const int bbase_c = 8192 + cur * 8192;
        // ---- 1) issue ks+1 global loads (no waits yet) ----
        float4 pf0, pf1;
        short8v wb0, wb1;
        const bool have_next = (ks + 1) < 32;
        bool next_a_ok = false;
        if (have_next) {
            const int kb2 = (ks + 1) * 32 + kq * 4;
            next_a_ok = (kb2 + 4 <= DIN);
            const int ko = next_a_ok ? kb2 : 0;
            pf0 = *reinterpret_cast<const float4*>(xb0 + ko);
            pf1 = *reinterpret_cast<const float4*>(xb1 + ko);
            const int gbase = (ks + 1) * 4;
            wb0 = *reinterpret_cast<const short8v*>(&wt[((size_t)(gbase + kcB0) * 256 + colB) * 8]);
            wb1 = *reinterpret_cast<const short8v*>(&wt[((size_t)(gbase + kcB1) * 256 + colB) * 8]);
        }
        // ---- 2) fragments + MFMA from buf[cur] ----
        short8v a[4], b[4];
        #pragma unroll
        for (int mi = 0; mi < 4; ++mi)
            a[mi] = *reinterpret_cast<const short8v*>(&smem[abase_c + ((size_t)kc * 128 + wm + mi * 16 + lr) * 8]);
        #pragma unroll
        for (int ni = 0; ni < 4; ++ni)
            b[ni] = *reinterpret_cast<const short8v*>(&smem[bbase_c + ((size_t)kc * 256 + wn + ni * 16 + lr) * 8]);
        #pragma unroll
        for (int mi = 0; mi < 4; ++mi)
            #pragma unroll
            for (int ni = 0; ni < 4; ++ni)
                acc[mi][ni] = __builtin_amdgcn_mfma_f32_16x16x32_bf16(a[mi], b[ni], acc[mi][ni], 0, 0, 0);
        // ---- 3) convert + ds_write stage data into buf[nxt] ----
        if (have_next) {
            const int abase_n = nxt * 4096;
            const int bbase_n = 8192 + nxt * 8192;
            short4v p0, p1;
            if (next_a_ok) {
                p0[0] = f2bf(pf0.x); p0[1] = f2bf(pf0.y); p0[2] = f2bf(pf0.z); p0[3] = f2bf(pf0.w);
                p1[0] = f2bf(pf1.x); p1[1] = f2bf(pf1.y); p1[2] = f2bf(pf1.z); p1[3] = f2bf(pf1.w);
            } else {
                p0 = (short4v){0, 0, 0, 0};
                p1 = (short4v){0, 0, 0, 0};
            }
            *reinterpret_cast<short4v*>(&smem[abase_n + aoff0]) = p0;
            *reinterpret_cast<short4v*>(&smem[abase_n + aoff1]) = p1;
            *reinterpret_cast<short8v*>(&smem[bbase_n + boff0]) = wb0;
            *reinterpret_cast<short8v*>(&smem[bbase_n + boff1]) = wb1;
        }
        // ---- 4) single barrier per K-step ----
        __syncthreads();
    }

    // ---- epilogue: BN + ELU -> bf16, staged via LDS, coalesced h1bf rows ----
    float sc[4], sh[4];
    #pragma unroll
    for (int ni = 0; ni < 4; ++ni) {
        const int col = wn + ni * 16 + lr;
        const float s = rsqrtf(v[col] + BN_EPS) * g[col];
        sc[ni] = s;
        sh[ni] = (bias[col] - m[col]) * s + bb[col];
    }
    #pragma unroll
    for (int p = 0; p < 2; ++p) {
        __syncthreads();   // staging area free (prev pass writes / K-loop done)
        if ((wave >> 2) == p) {
            #pragma unroll
            for (int mi = 0; mi < 4; ++mi) {
                #pragma unroll
                for (int j = 0; j < 4; ++j) {
                    const int lrow = mi * 16 + (lane >> 4) * 4 + j;   // 0..63
                    #pragma unroll
                    for (int ni = 0; ni < 4; ++ni) {
                        const float y = acc[mi][ni][j] * sc[ni] + sh[ni];
                        smem[lrow * 256 + wn + ni * 16 + lr] = f2bf(elu_f(y));
                    }
                }
            }
        }
        __syncthreads();
        for (int idx = t; idx < 2048; idx += 512) {
            const int r = idx >> 5;           // 0..63
            const int c8 = (idx & 31) * 8;    // 0..248
            const int row = row0 + p * 64 + r;
            if (row < NN)
                *reinterpret_cast<short8v*>(&h1bf[(size_t)row * 256 + c8]) =
                    *reinterpret_cast<const short8v*>(&smem[r * 256 + c8]);
        }
    }
}

// ---------------- encoder L1: h1bf[N,256] @ w[256,64] + BN + ELU -> feat, featbf, out ----------------
__global__ __launch_bounds__(256) void k_enc1(
    const short* __restrict__ h1bf, const float* __restrict__ w, const float* __restrict__ bias,
    const float* __restrict__ g, const float* __restrict__ bb,
    const float* __restrict__ m, const float* __restrict__ v,
    float* __restrict__ feat, short* __restrict__ featbf, float* __restrict__ out)
{
    __shared__ short hs[32 * 256];
    const int t = threadIdx.x;
    const int row0 = blockIdx.x * 32;
    const int j0 = t & 31;
    const int r0 = (t >> 5) * 4;
    float acc[4][2] = {};
    for (int idx = t; idx < 1024; idx += 256) {
        const int r = idx >> 5, c8 = idx & 31;
        *reinterpret_cast<short8v*>(&hs[r * 256 + c8 * 8]) =
            *reinterpret_cast<const short8v*>(&h1bf[(size_t)(row0 + r) * 256 + c8 * 8]);
    }
    __syncthreads();
    #pragma unroll 1
    for (int k = 0; k < 256; k += 8) {
        float wv[8][2];
        #pragma unroll
        for (int kk = 0; kk < 8; ++kk) {
            wv[kk][0] = w[(k + kk) * 64 + j0];
            wv[kk][1] = w[(k + kk) * 64 + j0 + 32];
        }
        #pragma unroll
        for (int r = 0; r < 4; ++r) {
            const short8v hv = *reinterpret_cast<const short8v*>(&hs[(r0 + r) * 256 + k]);
            #pragma unroll
            for (int kk = 0; kk < 8; ++kk) {
                const float xa = b2f(hv[kk]);
                acc[r][0] = fmaf(xa, wv[kk][0], acc[r][0]);
                acc[r][1] = fmaf(xa, wv[kk][1], acc[r][1]);
            }
        }
    }
    #pragma unroll
    for (int c = 0; c < 2; ++c) {
        const int j = j0 + 32 * c;
        const float sc = rsqrtf(v[j] + BN_EPS) * g[j];
        const float sh = (bias[j] - m[j]) * sc + bb[j];
        #pragma unroll
        for (int r = 0; r < 4; ++r) {
            const size_t rowi = row0 + r0 + r;
            const float y = elu_f(acc[r][c] * sc + sh);
            feat[rowi * 64 + j] = y;
            featbf[rowi * 64 + j] = f2bf(y);
            out[OFX + rowi * 64 + j] = y;
            out[OZ + rowi * 80 + j] = y;
        }
    }
}

// ---------------- GCN: gather featbf (64-dim bf16) FIRST (linearity) ----------------
__global__ __launch_bounds__(256) void k_feat_gather(
    const unsigned* __restrict__ featp, const float* __restrict__ deg,
    const int* __restrict__ off, const int2* __restrict__ csr_e,
    float* __restrict__ aggF)
{
    const int t = threadIdx.x;
    const int node = blockIdx.x * 8 + (t >> 5);   // grid = NN/8
    const int lane = t & 31;                       // feats 2*lane, 2*lane+1
    const float dg = deg[node];
    const float dinv = 1.0f / dg;
    const unsigned ps = featp[(size_t)node * 32 + lane];
    float a0 = b2f_lo(ps) * dinv;
    float a1 = b2f_hi(ps) * dinv;
    const int beg = off[node];
    const int end = beg + ((int)dg - 1);
    for (int s = beg; s < end; ++s) {
        const int2 e = csr_e[s];
        const float w = __int_as_float(e.y);
        const unsigned p = featp[(size_t)e.x * 32 + lane];
        a0 = fmaf(b2f_lo(p), w, a0);
        a1 = fmaf(b2f_hi(p), w, a1);
    }
    float2 o; o.x = a0; o.y = a1;
    *reinterpret_cast<float2*>(&aggF[(size_t)node * 64 + lane * 2]) = o;
}

// ---------------- fused conv+mlp projection: aggF -> (cmat in LDS) -> m2bf ----------------
__global__ __launch_bounds__(256) void k_conv_mlp_proj(
    const float* __restrict__ aggF, const float* __restrict__ w, const float* __restrict__ cb,
    const float* __restrict__ g, const float* __restrict__ bb,
    const float* __restrict__ m, const float* __restrict__ v,
    const float* __restrict__ mw, const float* __restrict__ lw,
    short* __restrict__ m2bf)
{
    __shared__ float fs[32 * 64];
    __shared__ float cs[32 * 128];
    const int t = threadIdx.x;
    const int row0 = blockIdx.x * 32;
    // ---- phase 1: conv GEMM (K=64) + bias + BN + ReLU -> cs ----
    {
        const int j0 = t & 63;
        const int r0 = (t >> 6) * 8;
        float acc[8][2] = {};
        for (int idx = t; idx < 512; idx += 256) {
            const int r = idx >> 4, c4 = idx & 15;
            *reinterpret_cast<float4*>(&fs[r * 64 + c4 * 4]) =
                *reinterpret_cast<const float4*>(&aggF[(size_t)(row0 + r) * 64 + c4 * 4]);
        }
        __syncthreads();
        #pragma unroll 1
        for (int k = 0; k < 64; k += 4) {
            float wv[4][2];
            #pragma unroll
            for (int kk = 0; kk < 4; ++kk) {
                wv[kk][0] = w[(k + kk) * 128 + j0];
                wv[kk][1] = w[(k + kk) * 128 + j0 + 64];
            }
            #pragma unroll
            for (int r = 0; r < 8; ++r) {
                const float4 xv = *reinterpret_cast<const float4*>(&fs[(r0 + r) * 64 + k]);
                const float xa[4] = {xv.x, xv.y, xv.z, xv.w};
                #pragma unroll
                for (int kk = 0; kk < 4; ++kk) {
                    acc[r][0] = fmaf(xa[kk], wv[kk][0], acc[r][0]);
                    acc[r][1] = fmaf(xa[kk], wv[kk][1], acc[r][1]);
                }
            }
        }
        #pragma unroll
        for (int c = 0; c < 2; ++c) {
            const int j = j0 + 64 * c;
            const float sc = rsqrtf(v[j] + BN_EPS) * g[j];
            const float sh = bb[j] - m[j] * sc;
            const float cbj = cb[j];
            #pragma unroll
            for (int r = 0; r < 8; ++r) {
                const float val = acc[r][c] + cbj;
                cs[(r0 + r) * 128 + j] = fmaxf(fmaf(val, sc, sh), 0.f);
            }
        }
    }
    __syncthreads();
    // ---- phase 2: mlp GEMM (K=128) from cs -> m2bf ----
    {
        const int j0 = t & 15;
        const int r0 = (t >> 4) * 2;
        float acc[2][2] = {};
        #pragma unroll 1
        for (int k = 0; k < 128; k += 4) {
            float wv[4][2];
            #pragma unroll
            for (int kk = 0; kk < 4; ++kk) {
                wv[kk][0] = mw[(k + kk) * 16 + j0];
                wv[kk][1] = lw[(k + kk) * 16 + j0];
            }
            #pragma unroll
            for (int r = 0; r < 2; ++r) {
                const float4 xv = *reinterpret_cast<const float4*>(&cs[(r0 + r) * 128 + k]);
                const float xa[4] = {xv.x, xv.y, xv.z, xv.w};
                #pragma unroll
                for (int kk = 0; kk < 4; ++kk) {
                    acc[r][0] = fmaf(xa[kk], wv[kk][0], acc[r][0]);
                    acc[r][1] = fmaf(xa[kk], wv[kk][1], acc[r][1]);
                }
            }
        }
        #pragma unroll
        for (int r = 0; r < 2; ++r) {
            const size_t rowi = row0 + r0 + r;
            m2bf[rowi * 32 + j0] = f2bf(acc[r][0]);
            m2bf[rowi * 32 + 16 + j0] = f2bf(acc[r][1]);
        }
    }
}

// ---------------- CSR gather mean|logvar (32 bf16 feats) + self-loop + bias ----------------
__global__ __launch_bounds__(256) void k_mlp_gather(
    const unsigned* __restrict__ m2p, const float* __restrict__ deg,
    const int* __restrict__ off, const int2* __restrict__ csr_e,
    const float* __restrict__ mb, const float* __restrict__ lb,
    float* __restrict__ agg2)
{
    const int t = threadIdx.x;
    const int node = blockIdx.x * 16 + (t >> 4);   // grid = NN/16
    const int lane = t & 15;                        // feats 2*lane, 2*lane+1
    const int f0 = lane * 2, f1 = lane * 2 + 1;
    const float dg = deg[node];
    const float dinv = 1.0f / dg;
    const float b0 = (f0 < 16) ? mb[f0] : lb[f0 - 16];
    const float b1 = (f1 < 16) ? mb[f1] : lb[f1 - 16];
    const unsigned ps = m2p[(size_t)node * 16 + lane];
    float a0 = fmaf(b2f_lo(ps), dinv, b0);
    float a1 = fmaf(b2f_hi(ps), dinv, b1);
    const int beg = off[node];
    const int end = beg + ((int)dg - 1);
    for (int s = beg; s < end; ++s) {
        const int2 e = csr_e[s];
        const float w = __int_as_float(e.y);
        const unsigned p = m2p[(size_t)e.x * 16 + lane];
        a0 = fmaf(b2f_lo(p), w, a0);
        a1 = fmaf(b2f_hi(p), w, a1);
    }
    float2 o; o.x = a0; o.y = a1;
    *reinterpret_cast<float2*>(&agg2[(size_t)node * 32 + lane * 2]) = o;
}

// ---------------- finalize pre: mu/logvar/z writes, dec0 -> d0bf (bf16), q ----------------
__global__ __launch_bounds__(256) void k_final_pre(
    const float* __restrict__ feat, const float* __restrict__ agg2,
    const float* __restrict__ d0w, const float* __restrict__ d0b,
    const float* __restrict__ g, const float* __restrict__ bb,
    const float* __restrict__ m, const float* __restrict__ v,
    const float* __restrict__ cluster,
    short* __restrict__ d0bf,
    float* __restrict__ out)
{
    __shared__ float zs[8][80];
    __shared__ float qs[8][15];
    const int t = threadIdx.x;
    const int row0 = blockIdx.x * 8;

    for (int idx = t; idx < 512; idx += 256) {
        const int r = idx >> 6, k = idx & 63;
        zs[r][k] = feat[(size_t)(row0 + r) * 64 + k];
    }
    if (t < 128) {
        const int r = t >> 4, k = t & 15;
        const size_t rowi = row0 + r;
        const float muv = agg2[rowi * 32 + k];
        const float lv = agg2[rowi * 32 + 16 + k];
        zs[r][64 + k] = muv;
        out[OMU + rowi * 16 + k] = muv;
        out[OGZ + rowi * 16 + k] = muv;
        out[OZ + rowi * 80 + 64 + k] = muv;
        out[OLV + rowi * 16 + k] = lv;
    }
    __syncthreads();

    // dec0: d0 = ELU(BN(z @ d0w + d0b)) -> bf16 global
    for (int idx = t; idx < 512; idx += 256) {
        const int r = idx >> 6, n = idx & 63;
        float acc = 0.f;
        #pragma unroll
        for (int k = 0; k < 80; k += 4) {
            const float4 zv = *reinterpret_cast<const float4*>(&zs[r][k]);
            acc = fmaf(zv.x, d0w[(k + 0) * 64 + n], acc);
            acc = fmaf(zv.y, d0w[(k + 1) * 64 + n], acc);
            acc = fmaf(zv.z, d0w[(k + 2) * 64 + n], acc);
            acc = fmaf(zv.w, d0w[(k + 3) * 64 + n], acc);
        }
        acc += d0b[n];
        const float sc = rsqrtf(v[n] + BN_EPS) * g[n];
        const float y = elu_f((acc - m[n]) * sc + bb[n]);
        d0bf[(size_t)(row0 + r) * 64 + n] = f2bf(y);
    }

    // student-t q
    if (t < 120) {
        const int r = t / 15, c = t % 15;
        float zz = 0.f, cc = 0.f, dot = 0.f;
        #pragma unroll 1
        for (int k = 0; k < 80; ++k) {
            const float zv = zs[r][k];
            const float cv = cluster[c * 80 + k];
            zz = fmaf(zv, zv, zz);
            cc = fmaf(cv, cv, cc);
            dot = fmaf(zv, cv, dot);
        }
        const float dist = fmaxf(zz + cc - 2.f * dot, 0.f);
        qs[r][c] = powf(1.0f / (1.0f + dist / 0.9f + 1e-8f), 0.95f);
    }
    __syncthreads();
    if (t < 120) {
        const int r = t / 15, c = t % 15;
        float s = 0.f;
        #pragma unroll
        for (int c2 = 0; c2 < 15; ++c2) s += qs[r][c2];
        out[OQ + (size_t)(row0 + r) * 15 + c] = qs[r][c] / s;
    }
}

// ---------------- dec1 via MFMA: de_feat = d0 @ d1w + d1b ----------------
// 128x128 tiles, 4 waves 2x2, K=64; epilogue stages the f32 tile (+bias) in
// LDS then writes fully-coalesced rows.
__global__ __launch_bounds__(256) void k_dec1_mfma(
    const short* __restrict__ d0bf, const short* __restrict__ wt2,
    const float* __restrict__ d1b, float* __restrict__ out)
{
    __shared__ float ots[128 * 128];   // 64 KB
    const int t = threadIdx.x;
    const int lane = t & 63;
    const int wave = t >> 6;
    const int wm = (wave >> 1) * 64;
    const int wn = (wave & 1) * 64;
    const int row0 = blockIdx.x * 128;
    const int col0 = blockIdx.y * 128;
    const int kc = lane >> 4;
    const int lr = lane & 15;

    f32x4 acc[4][4];
    #pragma unroll
    for (int mi = 0; mi < 4; ++mi)
        #pragma unroll
        for (int ni = 0; ni < 4; ++ni)
            acc[mi][ni] = (f32x4){0.f, 0.f, 0.f, 0.f};

    #pragma unroll
    for (int ks = 0; ks < 2; ++ks) {
        const int k0 = ks * 32 + kc * 8;
        short8v a[4], b[4];
        #pragma unroll
        for (int mi = 0; mi < 4; ++mi) {
            const int row = row0 + wm + mi * 16 + lr;
            if (row < NN)
                a[mi] = *reinterpret_cast<const short8v*>(&d0bf[(size_t)row * 64 + k0]);
            else
                a[mi] = (short8v){0, 0, 0, 0, 0, 0, 0, 0};
        }
        #pragma unroll
        for (int ni = 0; ni < 4; ++ni) {
            const int col = col0 + wn + ni * 16 + lr;
            b[ni] = *reinterpret_cast<const short8v*>(&wt2[(size_t)col * 64 + k0]);
        }
        #pragma unroll
        for (int mi = 0; mi < 4; ++mi)
            #pragma unroll
            for (int ni = 0; ni < 4; ++ni)
                acc[mi][ni] = __builtin_amdgcn_mfma_f32_16x16x32_bf16(a[mi], b[ni], acc[mi][ni], 0, 0, 0);
    }

    // ---- stage tile (+bias) into LDS ----
    #pragma unroll
    for (int ni = 0; ni < 4; ++ni) {
        const int lcol = wn + ni * 16 + lr;            // 0..127 within tile
        const int gcol = col0 + lcol;
        const float bv = d1b[(gcol < DIN) ? gcol : (DIN - 1)];
        #pragma unroll
        for (int mi = 0; mi < 4; ++mi) {
            #pragma unroll
            for (int j = 0; j < 4; ++j) {
                const int lrow = wm + mi * 16 + (lane >> 4) * 4 + j;   // 0..127
                ots[lrow * 128 + lcol] = acc[mi][ni][j] + bv;
            }
        }
    }
    __syncthreads();

    // ---- coalesced global write: 128 rows x 128 cols, float4 per thread ----
    for (int idx = t; idx < 128 * 32; idx += 256) {
        const int r = idx >> 5;           // 0..127
        const int c4 = (idx & 31) * 4;    // 0..124
        const int row = row0 + r;
        const int col = col0 + c4;
        if (row < NN && col < DIN) {
            const float4 val = *reinterpret_cast<const float4*>(&ots[r * 128 + c4]);
            *reinterpret_cast<float4*>(&out[ODE + (size_t)row * DIN + col]) = val;
        }
    }
}

extern "C" void kernel_launch(void* const* d_in, const int* in_sizes, int n_in,
                              void* d_out, int out_size, void* d_ws, size_t ws_size,
                              hipStream_t stream)
{
    const float* x       = (const float*)d_in[0];
    const void*  ei      = d_in[1];
    const float* enc0_w  = (const float*)d_in[2];
    const float* enc0_b  = (const float*)d_in[3];
    const float* enc0_g  = (const float*)d_in[4];
    const float* enc0_bb = (const float*)d_in[5];
    const float* enc0_m  = (const float*)d_in[6];
    const float* enc0_v  = (const float*)d_in[7];
    const float* enc1_w  = (const float*)d_in[8];
    const float* enc1_b  = (const float*)d_in[9];
    const float* enc1_g  = (const float*)d_in[10];
    const float* enc1_bb = (const float*)d_in[11];
    const float* enc1_m  = (const float*)d_in[12];
    const float* enc1_v  = (const float*)d_in[13];
    const float* conv_w  = (const float*)d_in[14];
    const float* conv_b  = (const float*)d_in[15];
    const float* conv_g  = (const float*)d_in[16];
    const float* conv_bb = (const float*)d_in[17];
    const float* conv_m  = (const float*)d_in[18];
    const float* conv_v  = (const float*)d_in[19];
    const float* mean_w  = (const float*)d_in[20];
    const float* mean_b  = (const float*)d_in[21];
    const float* logvar_w = (const float*)d_in[22];
    const float* logvar_b = (const float*)d_in[23];
    const float* dec0_w  = (const float*)d_in[24];
    const float* dec0_b  = (const float*)d_in[25];
    const float* dec0_g  = (const float*)d_in[26];
    const float* dec0_bb = (const float*)d_in[27];
    const float* dec0_m  = (const float*)d_in[28];
    const float* dec0_v  = (const float*)d_in[29];
    const float* dec1_w  = (const float*)d_in[30];
    const float* dec1_b  = (const float*)d_in[31];
    const float* cluster = (const float*)d_in[32];

    float* ws = (float*)d_ws;
    float* deg  = ws;                              // N
    float* feat = ws + NN;                         // 64N
    float* A    = ws + (size_t)65 * NN;            // 256N region, multi-use
    size_t base = (size_t)321 * NN;
    int*   off     = (int*)(ws + base);                        // N
    int*   cursor  = (int*)(ws + base + NN);                   // N
    int*   bsum    = (int*)(ws + base + 2 * (size_t)NN);       // 512
    int2*  csr_e   = (int2*)(ws + base + 2 * (size_t)NN + 512);            // E int2 (2E floats)
    short* wt      = (short*)(ws + base + 2 * (size_t)NN + 512 + 2 * (size_t)NE);  // 256*1024 bf16
    short* wt2     = wt + 262144;                               // 1024*64 bf16 (own buffer)
    int*   flag    = (int*)(ws + base + 2 * (size_t)NN + 512 + 2 * (size_t)NE + 131072 + 32768); // 1

    short* h1bf   = (short*)A;                      // N x 256 bf16 (A[0..128N) floats)
    short* featbf = (short*)(A + (size_t)128 * NN); // N x 64 bf16 (dead after feat_gather)
    float* aggF   = A;                              // N x 64 f32 (after h1bf dead)
    short* m2bf   = (short*)(A + (size_t)128 * NN); // N x 32 bf16 (featbf region, dead by then)
    float* agg2   = A + (size_t)32 * NN;            // N x 32 f32 (aggF dead after conv_mlp_proj)
    short* d0bf   = (short*)(A + (size_t)64 * NN);  // N x 64 bf16

    float* out = (float*)d_out;

    k_deg_init<<<NB, 256, 0, stream>>>((const int*)ei, deg, flag);
    k_deg_accum<<<NE / 256, 256, 0, stream>>>(ei, flag, deg);

    // CSR build (interleaved int2 edges)
    k_scan1<<<NB, 256, 0, stream>>>(deg, off, bsum, cursor);
    k_scan2<<<1, 512, 0, stream>>>(bsum);
    k_scan3<<<NB, 256, 0, stream>>>(off, bsum);
    k_fill<<<NE / 256, 256, 0, stream>>>(ei, flag, deg, off, cursor, csr_e);

    // weight prep (both) + enc0 via MFMA
    k_wts<<<1280, 256, 0, stream>>>(enc0_w, wt, dec1_w, wt2);
    k_enc0_mfma<<<(NN + 127) / 128, 512, 0, stream>>>(x, wt, enc0_b, enc0_g, enc0_bb, enc0_m, enc0_v, h1bf);

    k_enc1<<<NN / 32, 256, 0, stream>>>(h1bf, enc1_w, enc1_b, enc1_g, enc1_bb, enc1_m, enc1_v,
                                        feat, featbf, out);

    // GCN conv: aggregate bf16 feat first (linearity), then fused conv+mlp projections
    k_feat_gather<<<NN / 8, 256, 0, stream>>>((const unsigned*)featbf, deg, off, csr_e, aggF);
    k_conv_mlp_proj<<<NN / 32, 256, 0, stream>>>(aggF, conv_w, conv_b,
                                                 conv_g, conv_bb, conv_m, conv_v,
                                                 mean_w, logvar_w, m2bf);

    k_mlp_gather<<<NN / 16, 256, 0, stream>>>((const unsigned*)m2bf, deg, off, csr_e,
                                              mean_b, logvar_b, agg2);

    k_final_pre<<<NN / 8, 256, 0, stream>>>(feat, agg2, dec0_w, dec0_b, dec0_g, dec0_bb, dec0_m, dec0_v,
                                            cluster, d0bf, out);
    {
        dim3 grid((NN + 127) / 128, 8);
        k_dec1_mfma<<<grid, 256, 0, stream>>>(d0bf, wt2, dec1_b, out);
    }
}

// Round 22
// 903.517 us; speedup vs baseline: 1.0729x; 1.0729x over previous
//
#include <hip/hip_runtime.h>
#include <hip/hip_bf16.h>

#define NN 100000
#define NE 1600000
#define DIN 1000
#define BN_EPS 1e-3f
#define NB 391   // ceil(NN/256)

// output element offsets (concat of z, mu, logvar, de_feat, q, feat_x, gnn_z) — float32 out
#define OZ  ((size_t)0)
#define OMU ((size_t)NN*80)
#define OLV ((size_t)NN*96)
#define ODE ((size_t)NN*112)
#define OQ  ((size_t)NN*1112)
#define OFX ((size_t)NN*1127)
#define OGZ ((size_t)NN*1191)

typedef __attribute__((ext_vector_type(8))) short short8v;   // 8 bf16 (4 VGPRs)
typedef __attribute__((ext_vector_type(4))) short short4v;   // 4 bf16 (2 VGPRs)
typedef __attribute__((ext_vector_type(4))) float f32x4;     // MFMA accumulator

__device__ __forceinline__ float elu_f(float x) { return x > 0.f ? x : expf(x) - 1.f; }

// fp32 -> bf16 bits, round-to-nearest-even
__device__ __forceinline__ short f2bf(float f) {
    union { float f; unsigned u; } c; c.f = f;
    unsigned r = c.u + 0x7fffu + ((c.u >> 16) & 1u);
    return (short)(r >> 16);
}
// bf16 bits -> fp32
__device__ __forceinline__ float b2f(short s) {
    union { unsigned u; float f; } c; c.u = ((unsigned)(unsigned short)s) << 16; return c.f;
}
__device__ __forceinline__ float b2f_lo(unsigned p) {
    union { unsigned u; float f; } c; c.u = p << 16; return c.f;
}
__device__ __forceinline__ float b2f_hi(unsigned p) {
    union { unsigned u; float f; } c; c.u = p & 0xffff0000u; return c.f;
}

// Edge index may arrive as int32 or int64; logical element idx in flat (2*E) array.
__device__ __forceinline__ int edge_at(const void* ei, int is64, size_t idx) {
    if (is64) return (int)((const long long*)ei)[idx];
    return ((const int*)ei)[idx];
}

// ---------------- deg init + dtype detection (block 0) ----------------
__global__ __launch_bounds__(256) void k_deg_init(const int* __restrict__ ei,
                                                  float* __restrict__ deg, int* __restrict__ flag) {
    const int i = blockIdx.x * 256 + threadIdx.x;
    if (i < NN) deg[i] = 1.0f;
    if (blockIdx.x == 0) {
        __shared__ int nz;
        if (threadIdx.x == 0) nz = 0;
        __syncthreads();
        for (int j = threadIdx.x; j < 2048; j += 256)
            if (ei[2 * j + 1] != 0) nz = 1;
        __syncthreads();
        if (threadIdx.x == 0) flag[0] = (nz == 0) ? 1 : 0;  // 1 => int64
    }
}

__global__ __launch_bounds__(256) void k_deg_accum(const void* __restrict__ ei, const int* __restrict__ flag,
                                                   float* __restrict__ deg) {
    const int is64 = flag[0];
    int e = blockIdx.x * 256 + threadIdx.x;
    if (e < NE) atomicAdd(&deg[edge_at(ei, is64, (size_t)NE + e)], 1.0f);
}

// ---------------- CSR build: exclusive scan of in-edge counts ----------------
__global__ __launch_bounds__(256) void k_scan1(const float* __restrict__ deg, int* __restrict__ off,
                                               int* __restrict__ bsum, int* __restrict__ cursor) {
    __shared__ int s[256];
    const int t = threadIdx.x;
    const int i = blockIdx.x * 256 + t;
    const int vv = (i < NN) ? ((int)deg[i]) - 1 : 0;
    if (i < NN) cursor[i] = 0;
    s[t] = vv;
    __syncthreads();
    for (int d = 1; d < 256; d <<= 1) {
        const int u = (t >= d) ? s[t - d] : 0;
        __syncthreads();
        s[t] += u;
        __syncthreads();
    }
    if (i < NN) off[i] = s[t] - vv;           // exclusive, pre-block-offset
    if (t == 255) bsum[blockIdx.x] = s[t];    // block total
}

__global__ __launch_bounds__(512) void k_scan2(int* __restrict__ bsum) {
    __shared__ int s[512];
    const int t = threadIdx.x;
    const int vv = (t < NB) ? bsum[t] : 0;
    s[t] = vv;
    __syncthreads();
    for (int d = 1; d < 512; d <<= 1) {
        const int u = (t >= d) ? s[t - d] : 0;
        __syncthreads();
        s[t] += u;
        __syncthreads();
    }
    if (t < NB) bsum[t] = s[t] - vv;          // exclusive block prefix
}

__global__ __launch_bounds__(256) void k_scan3(int* __restrict__ off, const int* __restrict__ bsum) {
    const int i = blockIdx.x * 256 + threadIdx.x;
    if (i < NN) off[i] += bsum[blockIdx.x];
}

// CSR fill: just the src node id (weights folded into pre-scaled features)
__global__ __launch_bounds__(256) void k_fill(const void* __restrict__ ei, const int* __restrict__ flag,
                                              const int* __restrict__ off,
                                              int* __restrict__ cursor, int* __restrict__ csr_src) {
    const int is64 = flag[0];
    const int e = blockIdx.x * 256 + threadIdx.x;
    if (e >= NE) return;
    const int r = edge_at(ei, is64, e);
    const int c = edge_at(ei, is64, (size_t)NE + e);
    const int p = atomicAdd(&cursor[c], 1);
    csr_src[off[c] + p] = r;
}

// ---------------- merged weight prep ----------------
__global__ __launch_bounds__(256) void k_wts(const float* __restrict__ w0, short* __restrict__ wt,
                                             const float* __restrict__ w1, short* __restrict__ wt2) {
    const int bid = blockIdx.x;
    if (bid < 1024) {
        const int tid = bid * 256 + threadIdx.x;   // 256*1024 elements
        const int c = tid >> 10;
        const int k = tid & 1023;
        wt[((size_t)(k >> 3) * 256 + c) * 8 + (k & 7)] = (k < DIN) ? f2bf(w0[(size_t)k * 256 + c]) : (short)0;
    } else {
        const int tid = (bid - 1024) * 256 + threadIdx.x;   // 1024*64 elements
        const int c = tid >> 6;
        const int k = tid & 63;
        wt2[(size_t)c * 64 + k] = (c < DIN) ? f2bf(w1[(size_t)k * DIN + c]) : (short)0;
    }
}

// ---------------- encoder L0 via MFMA: h1bf = bf16(ELU(BN(x @ w))) ----------------
__global__ __launch_bounds__(512, 2) void k_enc0_mfma(
    const float* __restrict__ x, const short* __restrict__ wt, const float* __restrict__ bias,
    const float* __restrict__ g, const float* __restrict__ bb,
    const float* __restrict__ m, const float* __restrict__ v,
    short* __restrict__ h1bf)
{
    __shared__ short smem[24576];   // 48KB: As(2x4096) + Bs(2x8192); epilogue: 64x256 staging
    const int t = threadIdx.x;           // 0..511
    const int lane = t & 63;
    const int wave = t >> 6;             // 0..7
    const int wm = (wave >> 2) * 64;     // 0,64
    const int wn = (wave & 3) * 64;      // 0,64,128,192
    const int row0 = blockIdx.x * 128;

    f32x4 acc[4][4];
    #pragma unroll
    for (int mi = 0; mi < 4; ++mi)
        #pragma unroll
        for (int ni = 0; ni < 4; ++ni)
            acc[mi][ni] = (f32x4){0.f, 0.f, 0.f, 0.f};

    const int kq = t & 7;
    const int rA0 = t >> 3;              // 0..63
    const int rA1 = rA0 + 64;            // 64..127
    const int gr0 = (row0 + rA0 < NN) ? (row0 + rA0) : (NN - 1);
    const int gr1 = (row0 + rA1 < NN) ? (row0 + rA1) : (NN - 1);
    const float* xb0 = x + (size_t)gr0 * DIN;
    const float* xb1 = x + (size_t)gr1 * DIN;
    const size_t aoff0 = (((kq >> 1) * 128) + rA0) * 8 + (kq & 1) * 4;
    const size_t aoff1 = (((kq >> 1) * 128) + rA1) * 8 + (kq & 1) * 4;

    const int colB = t & 255;
    const int kcB0 = t >> 8;
    const int kcB1 = 2 + (t >> 8);
    const size_t boff0 = ((size_t)kcB0 * 256 + colB) * 8;
    const size_t boff1 = ((size_t)kcB1 * 256 + colB) * 8;

    const int kc = lane >> 4;    // 0..3
    const int lr = lane & 15;

    {
        const float4 f0 = *reinterpret_cast<const float4*>(xb0 + kq * 4);
        const float4 f1 = *reinterpret_cast<const float4*>(xb1 + kq * 4);
        short4v p0, p1;
        p0[0] = f2bf(f0.x); p0[1] = f2bf(f0.y); p0[2] = f2bf(f0.z); p0[3] = f2bf(f0.w);
        p1[0] = f2bf(f1.x); p1[1] = f2bf(f1.y); p1[2] = f2bf(f1.z); p1[3] = f2bf(f1.w);
        *reinterpret_cast<short4v*>(&smem[aoff0]) = p0;
        *reinterpret_cast<short4v*>(&smem[aoff1]) = p1;
        *reinterpret_cast<short8v*>(&smem[8192 + boff0]) =
            *reinterpret_cast<const short8v*>(&wt[((size_t)kcB0 * 256 + colB) * 8]);
        *reinterpret_cast<short8v*>(&smem[8192 + boff1]) =
            *reinterpret_cast<const short8v*>(&wt[((size_t)kcB1 * 256 + colB) * 8]);
    }
    __syncthreads();

    for (int ks = 0; ks < 32; ++ks) {
        const int cur = ks & 1;
        const int nxt = cur ^ 1;
        const int abase_c = cur * 4096;
        const int bbase_c = 8192 + cur * 8192;
        float4 pf0, pf1;
        short8v wb0, wb1;
        const bool have_next = (ks + 1) < 32;
        bool next_a_ok = false;
        if (have_next) {
            const int kb2 = (ks + 1) * 32 + kq * 4;
            next_a_ok = (kb2 + 4 <= DIN);
            const int ko = next_a_ok ? kb2 : 0;
            pf0 = *reinterpret_cast<const float4*>(xb0 + ko);
            pf1 = *reinterpret_cast<const float4*>(xb1 + ko);
            const int gbase = (ks + 1) * 4;
            wb0 = *reinterpret_cast<const short8v*>(&wt[((size_t)(gbase + kcB0) * 256 + colB) * 8]);
            wb1 = *reinterpret_cast<const short8v*>(&wt[((size_t)(gbase + kcB1) * 256 + colB) * 8]);
        }
        short8v a[4], b[4];
        #pragma unroll
        for (int mi = 0; mi < 4; ++mi)
            a[mi] = *reinterpret_cast<const short8v*>(&smem[abase_c + ((size_t)kc * 128 + wm + mi * 16 + lr) * 8]);
        #pragma unroll
        for (int ni = 0; ni < 4; ++ni)
            b[ni] = *reinterpret_cast<const short8v*>(&smem[bbase_c + ((size_t)kc * 256 + wn + ni * 16 + lr) * 8]);
        #pragma unroll
        for (int mi = 0; mi < 4; ++mi)
            #pragma unroll
            for (int ni = 0; ni < 4; ++ni)
                acc[mi][ni] = __builtin_amdgcn_mfma_f32_16x16x32_bf16(a[mi], b[ni], acc[mi][ni], 0, 0, 0);
        if (have_next) {
            const int abase_n = nxt * 4096;
            const int bbase_n = 8192 + nxt * 8192;
            short4v p0, p1;
            if (next_a_ok) {
                p0[0] = f2bf(pf0.x); p0[1] = f2bf(pf0.y); p0[2] = f2bf(pf0.z); p0[3] = f2bf(pf0.w);
                p1[0] = f2bf(pf1.x); p1[1] = f2bf(pf1.y); p1[2] = f2bf(pf1.z); p1[3] = f2bf(pf1.w);
            } else {
                p0 = (short4v){0, 0, 0, 0};
                p1 = (short4v){0, 0, 0, 0};
            }
            *reinterpret_cast<short4v*>(&smem[abase_n + aoff0]) = p0;
            *reinterpret_cast<short4v*>(&smem[abase_n + aoff1]) = p1;
            *reinterpret_cast<short8v*>(&smem[bbase_n + boff0]) = wb0;
            *reinterpret_cast<short8v*>(&smem[bbase_n + boff1]) = wb1;
        }
        __syncthreads();
    }

    // ---- epilogue: BN + ELU -> bf16, staged via LDS, coalesced h1bf rows ----
    float sc[4], sh[4];
    #pragma unroll
    for (int ni = 0; ni < 4; ++ni) {
        const int col = wn + ni * 16 + lr;
        const float s = rsqrtf(v[col] + BN_EPS) * g[col];
        sc[ni] = s;
        sh[ni] = (bias[col] - m[col]) * s + bb[col];
    }
    #pragma unroll
    for (int p = 0; p < 2; ++p) {
        __syncthreads();
        if ((wave >> 2) == p) {
            #pragma unroll
            for (int mi = 0; mi < 4; ++mi) {
                #pragma unroll
                for (int j = 0; j < 4; ++j) {
                    const int lrow = mi * 16 + (lane >> 4) * 4 + j;   // 0..63
                    #pragma unroll
                    for (int ni = 0; ni < 4; ++ni) {
                        const float y = acc[mi][ni][j] * sc[ni] + sh[ni];
                        smem[lrow * 256 + wn + ni * 16 + lr] = f2bf(elu_f(y));
                    }
                }
            }
        }
        __syncthreads();
        for (int idx = t; idx < 2048; idx += 512) {
            const int r = idx >> 5;           // 0..63
            const int c8 = (idx & 31) * 8;    // 0..248
            const int row = row0 + p * 64 + r;
            if (row < NN)
                *reinterpret_cast<short8v*>(&h1bf[(size_t)row * 256 + c8]) =
                    *reinterpret_cast<const short8v*>(&smem[r * 256 + c8]);
        }
    }
}

// ---------------- encoder L1: h1bf @ w + BN + ELU -> feat (f32), featbf (bf16, PRE-SCALED by rsqrt(deg)), out ----------------
__global__ __launch_bounds__(256) void k_enc1(
    const short* __restrict__ h1bf, const float* __restrict__ w, const float* __restrict__ bias,
    const float* __restrict__ g, const float* __restrict__ bb,
    const float* __restrict__ m, const float* __restrict__ v,
    const float* __restrict__ deg,
    float* __restrict__ feat, short* __restrict__ featbf, float* __restrict__ out)
{
    __shared__ short hs[32 * 256];
    const int t = threadIdx.x;
    const int row0 = blockIdx.x * 32;
    const int j0 = t & 31;
    const int r0 = (t >> 5) * 4;
    float acc[4][2] = {};
    for (int idx = t; idx < 1024; idx += 256) {
        const int r = idx >> 5, c8 = idx & 31;
        *reinterpret_cast<short8v*>(&hs[r * 256 + c8 * 8]) =
            *reinterpret_cast<const short8v*>(&h1bf[(size_t)(row0 + r) * 256 + c8 * 8]);
    }
    __syncthreads();
    #pragma unroll 1
    for (int k = 0; k < 256; k += 8) {
        float wv[8][2];
        #pragma unroll
        for (int kk = 0; kk < 8; ++kk) {
            wv[kk][0] = w[(k + kk) * 64 + j0];
            wv[kk][1] = w[(k + kk) * 64 + j0 + 32];
        }
        #pragma unroll
        for (int r = 0; r < 4; ++r) {
            const short8v hv = *reinterpret_cast<const short8v*>(&hs[(r0 + r) * 256 + k]);
            #pragma unroll
            for (int kk = 0; kk < 8; ++kk) {
                const float xa = b2f(hv[kk]);
                acc[r][0] = fmaf(xa, wv[kk][0], acc[r][0]);
                acc[r][1] = fmaf(xa, wv[kk][1], acc[r][1]);
            }
        }
    }
    #pragma unroll
    for (int c = 0; c < 2; ++c) {
        const int j = j0 + 32 * c;
        const float sc = rsqrtf(v[j] + BN_EPS) * g[j];
        const float sh = (bias[j] - m[j]) * sc + bb[j];
        #pragma unroll
        for (int r = 0; r < 4; ++r) {
            const size_t rowi = row0 + r0 + r;
            const float y = elu_f(acc[r][c] * sc + sh);
            const float rsq = rsqrtf(deg[rowi]);
            feat[rowi * 64 + j] = y;
            featbf[rowi * 64 + j] = f2bf(y * rsq);
            out[OFX + rowi * 64 + j] = y;
            out[OZ + rowi * 80 + j] = y;
        }
    }
}

// ---------------- GCN: gather pre-scaled featbf; aggF = rsqrt(deg_c) * (self + sum) ----------------
// 4-way unrolled edge loop: 4 independent random loads in flight per lane.
__global__ __launch_bounds__(256) void k_feat_gather(
    const unsigned* __restrict__ featp, const float* __restrict__ deg,
    const int* __restrict__ off, const int* __restrict__ csr_src,
    float* __restrict__ aggF)
{
    const int t = threadIdx.x;
    const int node = blockIdx.x * 8 + (t >> 5);   // grid = NN/8
    const int lane = t & 31;                       // feats 2*lane, 2*lane+1
    const float rsq = rsqrtf(deg[node]);
    const unsigned ps = featp[(size_t)node * 32 + lane];
    float ax = b2f_lo(ps), ay = b2f_hi(ps);        // self-term joins sum with coeff 1
    float bx = 0.f, by = 0.f, cx = 0.f, cy = 0.f, dx = 0.f, dy = 0.f;
    const int beg = off[node];
    const int end = beg + ((int)deg[node] - 1);
    int s = beg;
    for (; s + 4 <= end; s += 4) {
        const int r0 = csr_src[s], r1 = csr_src[s + 1], r2 = csr_src[s + 2], r3 = csr_src[s + 3];
        const unsigned p0 = featp[(size_t)r0 * 32 + lane];
        const unsigned p1 = featp[(size_t)r1 * 32 + lane];
        const unsigned p2 = featp[(size_t)r2 * 32 + lane];
        const unsigned p3 = featp[(size_t)r3 * 32 + lane];
        ax += b2f_lo(p0); ay += b2f_hi(p0);
        bx += b2f_lo(p1); by += b2f_hi(p1);
        cx += b2f_lo(p2); cy += b2f_hi(p2);
        dx += b2f_lo(p3); dy += b2f_hi(p3);
    }
    for (; s < end; ++s) {
        const unsigned p0 = featp[(size_t)csr_src[s] * 32 + lane];
        ax += b2f_lo(p0); ay += b2f_hi(p0);
    }
    float2 o;
    o.x = rsq * ((ax + bx) + (cx + dx));
    o.y = rsq * ((ay + by) + (cy + dy));
    *reinterpret_cast<float2*>(&aggF[(size_t)node * 64 + lane * 2]) = o;
}

// ---------------- fused conv+mlp projection: aggF -> (cmat in LDS) -> m2bf (PRE-SCALED) ----------------
__global__ __launch_bounds__(256) void k_conv_mlp_proj(
    const float* __restrict__ aggF, const float* __restrict__ w, const float* __restrict__ cb,
    const float* __restrict__ g, const float* __restrict__ bb,
    const float* __restrict__ m, const float* __restrict__ v,
    const float* __restrict__ mw, const float* __restrict__ lw,
    const float* __restrict__ deg,
    short* __restrict__ m2bf)
{
    __shared__ float fs[32 * 64];
    __shared__ float cs[32 * 128];
    const int t = threadIdx.x;
    const int row0 = blockIdx.x * 32;
    // ---- phase 1: conv GEMM (K=64) + bias + BN + ReLU -> cs ----
    {
        const int j0 = t & 63;
        const int r0 = (t >> 6) * 8;
        float acc[8][2] = {};
        for (int idx = t; idx < 512; idx += 256) {
            const int r = idx >> 4, c4 = idx & 15;
            *reinterpret_cast<float4*>(&fs[r * 64 + c4 * 4]) =
                *reinterpret_cast<const float4*>(&aggF[(size_t)(row0 + r) * 64 + c4 * 4]);
        }
        __syncthreads();
        #pragma unroll 1
        for (int k = 0; k < 64; k += 4) {
            float wv[4][2];
            #pragma unroll
            for (int kk = 0; kk < 4; ++kk) {
                wv[kk][0] = w[(k + kk) * 128 + j0];
                wv[kk][1] = w[(k + kk) * 128 + j0 + 64];
            }
            #pragma unroll
            for (int r = 0; r < 8; ++r) {
                const float4 xv = *reinterpret_cast<const float4*>(&fs[(r0 + r) * 64 + k]);
                const float xa[4] = {xv.x, xv.y, xv.z, xv.w};
                #pragma unroll
                for (int kk = 0; kk < 4; ++kk) {
                    acc[r][0] = fmaf(xa[kk], wv[kk][0], acc[r][0]);
                    acc[r][1] = fmaf(xa[kk], wv[kk][1], acc[r][1]);
                }
            }
        }
        #pragma unroll
        for (int c = 0; c < 2; ++c) {
            const int j = j0 + 64 * c;
            const float sc = rsqrtf(v[j] + BN_EPS) * g[j];
            const float sh = bb[j] - m[j] * sc;
            const float cbj = cb[j];
            #pragma unroll
            for (int r = 0; r < 8; ++r) {
                const float val = acc[r][c] + cbj;
                cs[(r0 + r) * 128 + j] = fmaxf(fmaf(val, sc, sh), 0.f);
            }
        }
    }
    __syncthreads();
    // ---- phase 2: mlp GEMM (K=128) from cs -> m2bf (scaled by rsqrt(deg)) ----
    {
        const int j0 = t & 15;
        const int r0 = (t >> 4) * 2;
        float acc[2][2] = {};
        #pragma unroll 1
        for (int k = 0; k < 128; k += 4) {
            float wv[4][2];
            #pragma unroll
            for (int kk = 0; kk < 4; ++kk) {
                wv[kk][0] = mw[(k + kk) * 16 + j0];
                wv[kk][1] = lw[(k + kk) * 16 + j0];
            }
            #pragma unroll
            for (int r = 0; r < 2; ++r) {
                const float4 xv = *reinterpret_cast<const float4*>(&cs[(r0 + r) * 128 + k]);
                const float xa[4] = {xv.x, xv.y, xv.z, xv.w};
                #pragma unroll
                for (int kk = 0; kk < 4; ++kk) {
                    acc[r][0] = fmaf(xa[kk], wv[kk][0], acc[r][0]);
                    acc[r][1] = fmaf(xa[kk], wv[kk][1], acc[r][1]);
                }
            }
        }
        #pragma unroll
        for (int r = 0; r < 2; ++r) {
            const size_t rowi = row0 + r0 + r;
            const float rsq = rsqrtf(deg[rowi]);
            m2bf[rowi * 32 + j0] = f2bf(acc[r][0] * rsq);
            m2bf[rowi * 32 + 16 + j0] = f2bf(acc[r][1] * rsq);
        }
    }
}

// ---------------- CSR gather mean|logvar (pre-scaled) + bias; agg2 = bias + rsq*(self+sum) ----------------
__global__ __launch_bounds__(256) void k_mlp_gather(
    const unsigned* __restrict__ m2p, const float* __restrict__ deg,
    const int* __restrict__ off, const int* __restrict__ csr_src,
    const float* __restrict__ mb, const float* __restrict__ lb,
    float* __restrict__ agg2)
{
    const int t = threadIdx.x;
    const int node = blockIdx.x * 16 + (t >> 4);   // grid = NN/16
    const int lane = t & 15;                        // feats 2*lane, 2*lane+1
    const int f0 = lane * 2, f1 = lane * 2 + 1;
    const float rsq = rsqrtf(deg[node]);
    const float b0 = (f0 < 16) ? mb[f0] : lb[f0 - 16];
    const float b1 = (f1 < 16) ? mb[f1] : lb[f1 - 16];
    const unsigned ps = m2p[(size_t)node * 16 + lane];
    float ax = b2f_lo(ps), ay = b2f_hi(ps);
    float bx = 0.f, by = 0.f, cx = 0.f, cy = 0.f, dx = 0.f, dy = 0.f;
    const int beg = off[node];
    const int end = beg + ((int)deg[node] - 1);
    int s = beg;
    for (; s + 4 <= end; s += 4) {
        const int r0 = csr_src[s], r1 = csr_src[s + 1], r2 = csr_src[s + 2], r3 = csr_src[s + 3];
        const unsigned p0 = m2p[(size_t)r0 * 16 + lane];
        const unsigned p1 = m2p[(size_t)r1 * 16 + lane];
        const unsigned p2 = m2p[(size_t)r2 * 16 + lane];
        const unsigned p3 = m2p[(size_t)r3 * 16 + lane];
        ax += b2f_lo(p0); ay += b2f_hi(p0);
        bx += b2f_lo(p1); by += b2f_hi(p1);
        cx += b2f_lo(p2); cy += b2f_hi(p2);
        dx += b2f_lo(p3); dy += b2f_hi(p3);
    }
    for (; s < end; ++s) {
        const unsigned p0 = m2p[(size_t)csr_src[s] * 16 + lane];
        ax += b2f_lo(p0); ay += b2f_hi(p0);
    }
    float2 o;
    o.x = fmaf(rsq, (ax + bx) + (cx + dx), b0);
    o.y = fmaf(rsq, (ay + by) + (cy + dy), b1);
    *reinterpret_cast<float2*>(&agg2[(size_t)node * 32 + lane * 2]) = o;
}

// ---------------- finalize pre: mu/logvar/z writes, dec0 -> d0bf (bf16), q ----------------
__global__ __launch_bounds__(256) void k_final_pre(
    const float* __restrict__ feat, const float* __restrict__ agg2,
    const float* __restrict__ d0w, const float* __restrict__ d0b,
    const float* __restrict__ g, const float* __restrict__ bb,
    const float* __restrict__ m, const float* __restrict__ v,
    const float* __restrict__ cluster,
    short* __restrict__ d0bf,
    float* __restrict__ out)
{
    __shared__ float zs[8][80];
    __shared__ float qs[8][15];
    const int t = threadIdx.x;
    const int row0 = blockIdx.x * 8;

    for (int idx = t; idx < 512; idx += 256) {
        const int r = idx >> 6, k = idx & 63;
        zs[r][k] = feat[(size_t)(row0 + r) * 64 + k];
    }
    if (t < 128) {
        const int r = t >> 4, k = t & 15;
        const size_t rowi = row0 + r;
        const float muv = agg2[rowi * 32 + k];
        const float lv = agg2[rowi * 32 + 16 + k];
        zs[r][64 + k] = muv;
        out[OMU + rowi * 16 + k] = muv;
        out[OGZ + rowi * 16 + k] = muv;
        out[OZ + rowi * 80 + 64 + k] = muv;
        out[OLV + rowi * 16 + k] = lv;
    }
    __syncthreads();

    // dec0: d0 = ELU(BN(z @ d0w + d0b)) -> bf16 global
    for (int idx = t; idx < 512; idx += 256) {
        const int r = idx >> 6, n = idx & 63;
        float acc = 0.f;
        #pragma unroll
        for (int k = 0; k < 80; k += 4) {
            const float4 zv = *reinterpret_cast<const float4*>(&zs[r][k]);
            acc = fmaf(zv.x, d0w[(k + 0) * 64 + n], acc);
            acc = fmaf(zv.y, d0w[(k + 1) * 64 + n], acc);
            acc = fmaf(zv.z, d0w[(k + 2) * 64 + n], acc);
            acc = fmaf(zv.w, d0w[(k + 3) * 64 + n], acc);
        }
        acc += d0b[n];
        const float sc = rsqrtf(v[n] + BN_EPS) * g[n];
        const float y = elu_f((acc - m[n]) * sc + bb[n]);
        d0bf[(size_t)(row0 + r) * 64 + n] = f2bf(y);
    }

    // student-t q
    if (t < 120) {
        const int r = t / 15, c = t % 15;
        float zz = 0.f, cc = 0.f, dot = 0.f;
        #pragma unroll 1
        for (int k = 0; k < 80; ++k) {
            const float zv = zs[r][k];
            const float cv = cluster[c * 80 + k];
            zz = fmaf(zv, zv, zz);
            cc = fmaf(cv, cv, cc);
            dot = fmaf(zv, cv, dot);
        }
        const float dist = fmaxf(zz + cc - 2.f * dot, 0.f);
        qs[r][c] = powf(1.0f / (1.0f + dist / 0.9f + 1e-8f), 0.95f);
    }
    __syncthreads();
    if (t < 120) {
        const int r = t / 15, c = t % 15;
        float s = 0.f;
        #pragma unroll
        for (int c2 = 0; c2 < 15; ++c2) s += qs[r][c2];
        out[OQ + (size_t)(row0 + r) * 15 + c] = qs[r][c] / s;
    }
}

// ---------------- dec1 via MFMA: de_feat = d0 @ d1w + d1b ----------------
__global__ __launch_bounds__(256) void k_dec1_mfma(
    const short* __restrict__ d0bf, const short* __restrict__ wt2,
    const float* __restrict__ d1b, float* __restrict__ out)
{
    __shared__ float ots[128 * 128];   // 64 KB
    const int t = threadIdx.x;
    const int lane = t & 63;
    const int wave = t >> 6;
    const int wm = (wave >> 1) * 64;
    const int wn = (wave & 1) * 64;
    const int row0 = blockIdx.x * 128;
    const int col0 = blockIdx.y * 128;
    const int kc = lane >> 4;
    const int lr = lane & 15;

    f32x4 acc[4][4];
    #pragma unroll
    for (int mi = 0; mi < 4; ++mi)
        #pragma unroll
        for (int ni = 0; ni < 4; ++ni)
            acc[mi][ni] = (f32x4){0.f, 0.f, 0.f, 0.f};

    #pragma unroll
    for (int ks = 0; ks < 2; ++ks) {
        const int k0 = ks * 32 + kc * 8;
        short8v a[4], b[4];
        #pragma unroll
        for (int mi = 0; mi < 4; ++mi) {
            const int row = row0 + wm + mi * 16 + lr;
            if (row < NN)
                a[mi] = *reinterpret_cast<const short8v*>(&d0bf[(size_t)row * 64 + k0]);
            else
                a[mi] = (short8v){0, 0, 0, 0, 0, 0, 0, 0};
        }
        #pragma unroll
        for (int ni = 0; ni < 4; ++ni) {
            const int col = col0 + wn + ni * 16 + lr;
            b[ni] = *reinterpret_cast<const short8v*>(&wt2[(size_t)col * 64 + k0]);
        }
        #pragma unroll
        for (int mi = 0; mi < 4; ++mi)
            #pragma unroll
            for (int ni = 0; ni < 4; ++ni)
                acc[mi][ni] = __builtin_amdgcn_mfma_f32_16x16x32_bf16(a[mi], b[ni], acc[mi][ni], 0, 0, 0);
    }

    // ---- stage tile (+bias) into LDS ----
    #pragma unroll
    for (int ni = 0; ni < 4; ++ni) {
        const int lcol = wn + ni * 16 + lr;            // 0..127 within tile
        const int gcol = col0 + lcol;
        const float bv = d1b[(gcol < DIN) ? gcol : (DIN - 1)];
        #pragma unroll
        for (int mi = 0; mi < 4; ++mi) {
            #pragma unroll
            for (int j = 0; j < 4; ++j) {
                const int lrow = wm + mi * 16 + (lane >> 4) * 4 + j;   // 0..127
                ots[lrow * 128 + lcol] = acc[mi][ni][j] + bv;
            }
        }
    }
    __syncthreads();

    // ---- coalesced global write ----
    for (int idx = t; idx < 128 * 32; idx += 256) {
        const int r = idx >> 5;           // 0..127
        const int c4 = (idx & 31) * 4;    // 0..124
        const int row = row0 + r;
        const int col = col0 + c4;
        if (row < NN && col < DIN) {
            const float4 val = *reinterpret_cast<const float4*>(&ots[r * 128 + c4]);
            *reinterpret_cast<float4*>(&out[ODE + (size_t)row * DIN + col]) = val;
        }
    }
}

extern "C" void kernel_launch(void* const* d_in, const int* in_sizes, int n_in,
                              void* d_out, int out_size, void* d_ws, size_t ws_size,
                              hipStream_t stream)
{
    const float* x       = (const float*)d_in[0];
    const void*  ei      = d_in[1];
    const float* enc0_w  = (const float*)d_in[2];
    const float* enc0_b  = (const float*)d_in[3];
    const float* enc0_g  = (const float*)d_in[4];
    const float* enc0_bb = (const float*)d_in[5];
    const float* enc0_m  = (const float*)d_in[6];
    const float* enc0_v  = (const float*)d_in[7];
    const float* enc1_w  = (const float*)d_in[8];
    const float* enc1_b  = (const float*)d_in[9];
    const float* enc1_g  = (const float*)d_in[10];
    const float* enc1_bb = (const float*)d_in[11];
    const float* enc1_m  = (const float*)d_in[12];
    const float* enc1_v  = (const float*)d_in[13];
    const float* conv_w  = (const float*)d_in[14];
    const float* conv_b  = (const float*)d_in[15];
    const float* conv_g  = (const float*)d_in[16];
    const float* conv_bb = (const float*)d_in[17];
    const float* conv_m  = (const float*)d_in[18];
    const float* conv_v  = (const float*)d_in[19];
    const float* mean_w  = (const float*)d_in[20];
    const float* mean_b  = (const float*)d_in[21];
    const float* logvar_w = (const float*)d_in[22];
    const float* logvar_b = (const float*)d_in[23];
    const float* dec0_w  = (const float*)d_in[24];
    const float* dec0_b  = (const float*)d_in[25];
    const float* dec0_g  = (const float*)d_in[26];
    const float* dec0_bb = (const float*)d_in[27];
    const float* dec0_m  = (const float*)d_in[28];
    const float* dec0_v  = (const float*)d_in[29];
    const float* dec1_w  = (const float*)d_in[30];
    const float* dec1_b  = (const float*)d_in[31];
    const float* cluster = (const float*)d_in[32];

    float* ws = (float*)d_ws;
    float* deg  = ws;                              // N
    float* feat = ws + NN;                         // 64N
    float* A    = ws + (size_t)65 * NN;            // 256N region, multi-use
    size_t base = (size_t)321 * NN;
    int*   off     = (int*)(ws + base);                        // N
    int*   cursor  = (int*)(ws + base + NN);                   // N
    int*   bsum    = (int*)(ws + base + 2 * (size_t)NN);       // 512
    int*   csr_src = (int*)(ws + base + 2 * (size_t)NN + 512);             // E ints (region holds 2E)
    short* wt      = (short*)(ws + base + 2 * (size_t)NN + 512 + 2 * (size_t)NE);  // 256*1024 bf16
    short* wt2     = wt + 262144;                               // 1024*64 bf16
    int*   flag    = (int*)(ws + base + 2 * (size_t)NN + 512 + 2 * (size_t)NE + 131072 + 32768); // 1

    short* h1bf   = (short*)A;                      // N x 256 bf16
    short* featbf = (short*)(A + (size_t)128 * NN); // N x 64 bf16 (pre-scaled)
    float* aggF   = A;                              // N x 64 f32 (after h1bf dead)
    short* m2bf   = (short*)(A + (size_t)128 * NN); // N x 32 bf16 (pre-scaled; featbf region)
    float* agg2   = A + (size_t)32 * NN;            // N x 32 f32
    short* d0bf   = (short*)(A + (size_t)64 * NN);  // N x 64 bf16

    float* out = (float*)d_out;

    k_deg_init<<<NB, 256, 0, stream>>>((const int*)ei, deg, flag);
    k_deg_accum<<<NE / 256, 256, 0, stream>>>(ei, flag, deg);

    // CSR build (src-only edges; norm folded into pre-scaled features)
    k_scan1<<<NB, 256, 0, stream>>>(deg, off, bsum, cursor);
    k_scan2<<<1, 512, 0, stream>>>(bsum);
    k_scan3<<<NB, 256, 0, stream>>>(off, bsum);
    k_fill<<<NE / 256, 256, 0, stream>>>(ei, flag, off, cursor, csr_src);

    // weight prep (both) + enc0 via MFMA
    k_wts<<<1280, 256, 0, stream>>>(enc0_w, wt, dec1_w, wt2);
    k_enc0_mfma<<<(NN + 127) / 128, 512, 0, stream>>>(x, wt, enc0_b, enc0_g, enc0_bb, enc0_m, enc0_v, h1bf);

    k_enc1<<<NN / 32, 256, 0, stream>>>(h1bf, enc1_w, enc1_b, enc1_g, enc1_bb, enc1_m, enc1_v, deg,
                                        feat, featbf, out);

    // GCN conv: unweighted gather of pre-scaled feats, then fused conv+mlp projections
    k_feat_gather<<<NN / 8, 256, 0, stream>>>((const unsigned*)featbf, deg, off, csr_src, aggF);
    k_conv_mlp_proj<<<NN / 32, 256, 0, stream>>>(aggF, conv_w, conv_b,
                                                 conv_g, conv_bb, conv_m, conv_v,
                                                 mean_w, logvar_w, deg, m2bf);

    k_mlp_gather<<<NN / 16, 256, 0, stream>>>((const unsigned*)m2bf, deg, off, csr_src,
                                              mean_b, logvar_b, agg2);

    k_final_pre<<<NN / 8, 256, 0, stream>>>(feat, agg2, dec0_w, dec0_b, dec0_g, dec0_bb, dec0_m, dec0_v,
                                            cluster, d0bf, out);
    {
        dim3 grid((NN + 127) / 128, 8);
        k_dec1_mfma<<<grid, 256, 0, stream>>>(d0bf, wt2, dec1_b, out);
    }
}